// Round 17
// baseline (82.979 us; speedup 1.0000x reference)
//
#include <hip/hip_runtime.h>

// GCN 2-layer forward, aggregate-first + bf16 dinv-prescaled gather.
// fused_layer now 512 threads / 64 nodes per block -> 32 waves/CU occupancy.
//   xh[r] = bf16(dinv_r * in_r);  S_c = dinv_c * sum xh_r;  z = relu(S@W + b)
// CSR via counting sort into fixed-capacity bucket regions (bucket = col>>8).

#define DF 64
#define XS_LD 68
#define ECHUNK 4096
#define BCAP 5120        // bucket region capacity (mean 4096 + 16 sigma)
#define LBLK 512         // fused layer block size
#define LNODES 64        // nodes per fused layer block

__device__ __forceinline__ unsigned short f2bf(float f) {
  union { float f; unsigned int u; } c; c.f = f;
  unsigned int r = c.u + 0x7FFFu + ((c.u >> 16) & 1u);   // RNE
  return (unsigned short)(r >> 16);
}
__device__ __forceinline__ float bflo(unsigned int u) {
  union { unsigned int u; float f; } c; c.u = u << 16; return c.f;
}
__device__ __forceinline__ float bfhi(unsigned int u) {
  union { unsigned int u; float f; } c; c.u = u & 0xFFFF0000u; return c.f;
}

// ---- stage 0: init bucket cursors ----
__global__ void init_cur_k(int* __restrict__ gcursor) {
  gcursor[threadIdx.x] = threadIdx.x * BCAP;
}

// ---- stage 1: partition edges into bucket regions (direct-index flush) ----
__global__ __launch_bounds__(256) void part_k(
    const int* __restrict__ rows, const int* __restrict__ cols,
    int* __restrict__ gcursor, unsigned int* __restrict__ bfile, int e_cnt)
{
  __shared__ int h[256];
  __shared__ int p[256];
  __shared__ int lb[256];
  __shared__ int cur[256];
  __shared__ int gb[256];
  __shared__ unsigned int buf[ECHUNK];
  const int tid = threadIdx.x;
  h[tid] = 0; __syncthreads();

  const int e0 = blockIdx.x * ECHUNK;
  const int m  = min(ECHUNK, e_cnt - e0);
  unsigned int pk[ECHUNK / 256];
  int bk[ECHUNK / 256];
#pragma unroll
  for (int j = 0; j < ECHUNK / 256; ++j) {
    int idx = j * 256 + tid;
    if (idx < m) {
      int c = cols[e0 + idx];
      int r = rows[e0 + idx];
      bk[j] = c >> 8;
      pk[j] = ((unsigned int)bk[j] << 24) | ((unsigned int)(c & 255) << 16) | (unsigned int)r;
      atomicAdd(&h[bk[j]], 1);
    } else bk[j] = -1;
  }
  __syncthreads();

  const int myc = h[tid];
  p[tid] = myc; __syncthreads();
  for (int off = 1; off < 256; off <<= 1) {
    int t = (tid >= off) ? p[tid - off] : 0;
    __syncthreads();
    p[tid] += t;
    __syncthreads();
  }
  const int ex = p[tid] - myc;
  lb[tid] = ex; cur[tid] = ex;
  if (myc > 0) gb[tid] = atomicAdd(&gcursor[tid], myc);
  __syncthreads();

#pragma unroll
  for (int j = 0; j < ECHUNK / 256; ++j)
    if (bk[j] >= 0) { int pos = atomicAdd(&cur[bk[j]], 1); buf[pos] = pk[j]; }
  __syncthreads();

  for (int i = tid; i < m; i += 256) {
    unsigned int v = buf[i];
    int b = (int)(v >> 24);
    bfile[gb[b] + (i - lb[b])] = v;
  }
}

// ---- stage 2: per-bucket counting sort -> csr16, base, cnt, dinv,
//      plus fused conversion x -> xh = bf16(dinv*x) ----
__global__ __launch_bounds__(256) void bucket_k(
    const unsigned int* __restrict__ bfile, const int* __restrict__ gcursor,
    unsigned short* __restrict__ csr16, int* __restrict__ basep,
    int* __restrict__ cntp, float* __restrict__ dinv,
    const float* __restrict__ x, uint4* __restrict__ xh, int n)
{
  __shared__ unsigned int ein[BCAP];
  __shared__ unsigned short eout[BCAP];
  __shared__ int h[256];
  __shared__ int p[256];
  __shared__ int cur[256];
  __shared__ float dvs[256];
  const int tid = threadIdx.x;
  const int b   = blockIdx.x;
  const int s   = b * BCAP;
  int L = gcursor[b] - s;
  if (L > BCAP) L = BCAP;

  for (int i = tid; i < L; i += 256) ein[i] = bfile[s + i];
  h[tid] = 0; __syncthreads();
  for (int i = tid; i < L; i += 256) atomicAdd(&h[(ein[i] >> 16) & 255], 1);
  __syncthreads();

  const int myc = h[tid];
  p[tid] = myc; __syncthreads();
  for (int off = 1; off < 256; off <<= 1) {
    int t = (tid >= off) ? p[tid - off] : 0;
    __syncthreads();
    p[tid] += t;
    __syncthreads();
  }
  const int ex = p[tid] - myc;
  cur[tid] = ex;
  __syncthreads();

  for (int i = tid; i < L; i += 256) {
    unsigned int pk = ein[i];
    int pos = atomicAdd(&cur[(pk >> 16) & 255], 1);
    eout[pos] = (unsigned short)(pk & 0xffffu);
  }
  __syncthreads();

  for (int i = tid; i < L; i += 256) csr16[s + i] = eout[i];

  const int node = b * 256 + tid;
  const float dvv = rsqrtf(1.0f + (float)myc);
  dvs[tid] = dvv;
  if (node < n) {
    basep[node] = s + ex;
    cntp[node]  = myc;
    dinv[node]  = dvv;
  }
  __syncthreads();

  const float4* x4 = (const float4*)x;
#pragma unroll
  for (int i = 0; i < 8; ++i) {
    int slot = i * 256 + tid;
    int ln = slot >> 3;
    int gn = b * 256 + ln;
    if (gn >= n) continue;
    int q = slot & 7;
    float4 v0 = x4[(size_t)gn * 16 + q * 2 + 0];
    float4 v1 = x4[(size_t)gn * 16 + q * 2 + 1];
    float dvx = dvs[ln];
    uint4 u;
    u.x = (unsigned int)f2bf(dvx * v0.x) | ((unsigned int)f2bf(dvx * v0.y) << 16);
    u.y = (unsigned int)f2bf(dvx * v0.z) | ((unsigned int)f2bf(dvx * v0.w) << 16);
    u.z = (unsigned int)f2bf(dvx * v1.x) | ((unsigned int)f2bf(dvx * v1.y) << 16);
    u.w = (unsigned int)f2bf(dvx * v1.z) | ((unsigned int)f2bf(dvx * v1.w) << 16);
    xh[(size_t)gn * 8 + q] = u;
  }
}

#define ACC8(acc, v) \
  acc[0] += bflo(v.x); acc[1] += bfhi(v.x); acc[2] += bflo(v.y); acc[3] += bfhi(v.y); \
  acc[4] += bflo(v.z); acc[5] += bfhi(v.z); acc[6] += bflo(v.w); acc[7] += bfhi(v.w);

// ---- fused layer: bf16 gather (8 lanes/node, 16B/lane), fp32 accum,
//      S tile -> LDS, in-block GEMM + bias + relu. 64 nodes / 512-thr block.
//      OUTBF=1: write bf16(dinv_c * relu) for next layer; else fp32. ----
template<int OUTBF>
__global__ __launch_bounds__(LBLK) void fused_layer_k(
    const uint4* __restrict__ inh, const float* __restrict__ W,
    const float* __restrict__ bias, const unsigned short* __restrict__ csr16,
    const int* __restrict__ basep, const int* __restrict__ cntp,
    const float* __restrict__ dinv, void* __restrict__ outp, int n)
{
  __shared__ float Ws[DF * XS_LD];
  __shared__ float Ss[LNODES * XS_LD];
  const int tid = threadIdx.x;

#pragma unroll
  for (int i = 0; i < 2; ++i) {
    const int f4 = tid + LBLK * i;       // 1024 float4 slots
    const int k  = f4 >> 4;
    const int c0 = (f4 & 15) * 4;
    *(float4*)(Ws + k * XS_LD + c0) = *(const float4*)(W + (size_t)f4 * 4);
  }

  const int nl   = tid >> 3;            // 0..63
  const int q    = tid & 7;             // 0..7
  const int node = blockIdx.x * LNODES + nl;
  const bool valid = (node < n);
  float dv = 0.f;

  if (valid) {
    float a[8] = {0,0,0,0,0,0,0,0};
    float b2[8] = {0,0,0,0,0,0,0,0};
    dv = dinv[node];
    {
      uint4 v = inh[(size_t)node * 8 + q];          // self term (prescaled)
      ACC8(a, v)
    }
    const int s = basep[node], c = cntp[node];
    int k = 0;
    for (; k + 4 <= c; k += 4) {
      int r0 = (int)csr16[s + k + 0], r1 = (int)csr16[s + k + 1];
      int r2 = (int)csr16[s + k + 2], r3 = (int)csr16[s + k + 3];
      uint4 v0 = inh[(size_t)r0 * 8 + q];
      uint4 v1 = inh[(size_t)r1 * 8 + q];
      uint4 v2 = inh[(size_t)r2 * 8 + q];
      uint4 v3 = inh[(size_t)r3 * 8 + q];
      ACC8(a, v0) ACC8(b2, v1) ACC8(a, v2) ACC8(b2, v3)
    }
    for (; k < c; ++k) {
      int r = (int)csr16[s + k];
      uint4 v = inh[(size_t)r * 8 + q];
      ACC8(a, v)
    }
    float4 s0 = make_float4(dv * (a[0] + b2[0]), dv * (a[1] + b2[1]),
                            dv * (a[2] + b2[2]), dv * (a[3] + b2[3]));
    float4 s1 = make_float4(dv * (a[4] + b2[4]), dv * (a[5] + b2[5]),
                            dv * (a[6] + b2[6]), dv * (a[7] + b2[7]));
    *(float4*)(Ss + nl * XS_LD + q * 8 + 0) = s0;
    *(float4*)(Ss + nl * XS_LD + q * 8 + 4) = s1;
  }
  __syncthreads();

  float4 o0 = ((const float4*)bias)[q * 2 + 0];
  float4 o1 = ((const float4*)bias)[q * 2 + 1];
#pragma unroll 16
  for (int k = 0; k < DF; ++k) {
    const float sk = Ss[nl * XS_LD + k];
    const float4 w0 = *(const float4*)(Ws + k * XS_LD + q * 8 + 0);
    const float4 w1 = *(const float4*)(Ws + k * XS_LD + q * 8 + 4);
    o0.x += sk * w0.x; o0.y += sk * w0.y; o0.z += sk * w0.z; o0.w += sk * w0.w;
    o1.x += sk * w1.x; o1.y += sk * w1.y; o1.z += sk * w1.z; o1.w += sk * w1.w;
  }
  if (valid) {
    o0.x = fmaxf(o0.x, 0.f); o0.y = fmaxf(o0.y, 0.f);
    o0.z = fmaxf(o0.z, 0.f); o0.w = fmaxf(o0.w, 0.f);
    o1.x = fmaxf(o1.x, 0.f); o1.y = fmaxf(o1.y, 0.f);
    o1.z = fmaxf(o1.z, 0.f); o1.w = fmaxf(o1.w, 0.f);
    if (OUTBF) {
      uint4 u;
      u.x = (unsigned int)f2bf(dv * o0.x) | ((unsigned int)f2bf(dv * o0.y) << 16);
      u.y = (unsigned int)f2bf(dv * o0.z) | ((unsigned int)f2bf(dv * o0.w) << 16);
      u.z = (unsigned int)f2bf(dv * o1.x) | ((unsigned int)f2bf(dv * o1.y) << 16);
      u.w = (unsigned int)f2bf(dv * o1.z) | ((unsigned int)f2bf(dv * o1.w) << 16);
      ((uint4*)outp)[(size_t)node * 8 + q] = u;
    } else {
      ((float4*)outp)[(size_t)node * 16 + q * 2 + 0] = o0;
      ((float4*)outp)[(size_t)node * 16 + q * 2 + 1] = o1;
    }
  }
}

extern "C" void kernel_launch(void* const* d_in, const int* in_sizes, int n_in,
                              void* d_out, int out_size, void* d_ws, size_t ws_size,
                              hipStream_t stream) {
  const float* x  = (const float*)d_in[0];
  const float* W1 = (const float*)d_in[1];
  const float* b1 = (const float*)d_in[2];
  const float* W2 = (const float*)d_in[3];
  const float* b2 = (const float*)d_in[4];
  const int*   ei = (const int*)d_in[5];

  const int n = in_sizes[0] / DF;        // 50000
  const int E = in_sizes[5] / 2;         // 800000
  const int* rows = ei;
  const int* cols = ei + E;
  const int nb = (n + 255) >> 8;         // 196 buckets
  const int eblocks = (E + ECHUNK - 1) / ECHUNK;

  char* w = (char*)d_ws;
  size_t off = 0;
  auto alloc = [&](size_t bytes) { char* p = w + off; off = (off + bytes + 255) & ~(size_t)255; return p; };
  float* dinv    = (float*)alloc((size_t)n * 4);
  int*   cntp    = (int*)  alloc((size_t)n * 4);
  int*   basep   = (int*)  alloc((size_t)n * 4);
  int*   gcursor = (int*)  alloc(256 * 4);
  unsigned int*   bfile = (unsigned int*)  alloc((size_t)nb * BCAP * 4);
  unsigned short* csr16 = (unsigned short*)alloc((size_t)nb * BCAP * 2 + 64);
  uint4* xh      = (uint4*)alloc((size_t)n * DF * 2);   // 6.4 MB bf16
  uint4* zh      = (uint4*)alloc((size_t)n * DF * 2);   // 6.4 MB bf16

  const int b256 = 256;

  // ---- CSR build + dinv + x conversion ----
  init_cur_k<<<1, 256, 0, stream>>>(gcursor);
  part_k<<<eblocks, b256, 0, stream>>>(rows, cols, gcursor, bfile, E);
  bucket_k<<<nb, b256, 0, stream>>>(bfile, gcursor, csr16, basep, cntp, dinv, x, xh, n);

  const int lay_blocks = (n + LNODES - 1) / LNODES;   // 782

  // ---- layer 1: xh -> zh (bf16, prescaled) ----
  fused_layer_k<1><<<lay_blocks, LBLK, 0, stream>>>(xh, W1, b1, csr16, basep, cntp, dinv, zh, n);
  // ---- layer 2: zh -> d_out (fp32) ----
  fused_layer_k<0><<<lay_blocks, LBLK, 0, stream>>>(zh, W2, b2, csr16, basep, cntp, dinv, d_out, n);
}

// Round 18
// 77.862 us; speedup vs baseline: 1.0657x; 1.0657x over previous
//
#include <hip/hip_runtime.h>

// GCN 2-layer forward, aggregate-first + bf16 dinv-prescaled gather.
// Build chain widened to 512 threads/block (grid was parallelism-starved).
//   xh[r] = bf16(dinv_r * in_r);  S_c = dinv_c * sum xh_r;  z = relu(S@W + b)
// CSR via counting sort into fixed-capacity bucket regions (bucket = col>>8).

#define DF 64
#define XS_LD 68
#define ECHUNK 4096
#define BCAP 5120        // bucket region capacity (mean 4096 + 16 sigma)

__device__ __forceinline__ unsigned short f2bf(float f) {
  union { float f; unsigned int u; } c; c.f = f;
  unsigned int r = c.u + 0x7FFFu + ((c.u >> 16) & 1u);   // RNE
  return (unsigned short)(r >> 16);
}
__device__ __forceinline__ float bflo(unsigned int u) {
  union { unsigned int u; float f; } c; c.u = u << 16; return c.f;
}
__device__ __forceinline__ float bfhi(unsigned int u) {
  union { unsigned int u; float f; } c; c.u = u & 0xFFFF0000u; return c.f;
}

// ---- stage 0: init bucket cursors ----
__global__ void init_cur_k(int* __restrict__ gcursor) {
  gcursor[threadIdx.x] = threadIdx.x * BCAP;
}

// ---- stage 1: partition edges into bucket regions (512 thr, direct-index flush) ----
__global__ __launch_bounds__(512) void part_k(
    const int* __restrict__ rows, const int* __restrict__ cols,
    int* __restrict__ gcursor, unsigned int* __restrict__ bfile, int e_cnt)
{
  __shared__ int h[256];
  __shared__ int p[256];
  __shared__ int lb[256];
  __shared__ int cur[256];
  __shared__ int gb[256];
  __shared__ unsigned int buf[ECHUNK];
  const int tid = threadIdx.x;
  if (tid < 256) h[tid] = 0;
  __syncthreads();

  const int e0 = blockIdx.x * ECHUNK;
  const int m  = min(ECHUNK, e_cnt - e0);
  unsigned int pk[ECHUNK / 512];
  int bk[ECHUNK / 512];
#pragma unroll
  for (int j = 0; j < ECHUNK / 512; ++j) {
    int idx = j * 512 + tid;
    if (idx < m) {
      int c = cols[e0 + idx];
      int r = rows[e0 + idx];
      bk[j] = c >> 8;
      pk[j] = ((unsigned int)bk[j] << 24) | ((unsigned int)(c & 255) << 16) | (unsigned int)r;
      atomicAdd(&h[bk[j]], 1);
    } else bk[j] = -1;
  }
  __syncthreads();

  const int myc = (tid < 256) ? h[tid] : 0;
  if (tid < 256) p[tid] = myc;
  __syncthreads();
  for (int off = 1; off < 256; off <<= 1) {
    int t = (tid >= off && tid < 256) ? p[tid - off] : 0;
    __syncthreads();
    if (tid < 256) p[tid] += t;
    __syncthreads();
  }
  if (tid < 256) {
    const int ex = p[tid] - myc;
    lb[tid] = ex; cur[tid] = ex;
    if (myc > 0) gb[tid] = atomicAdd(&gcursor[tid], myc);
  }
  __syncthreads();

#pragma unroll
  for (int j = 0; j < ECHUNK / 512; ++j)
    if (bk[j] >= 0) { int pos = atomicAdd(&cur[bk[j]], 1); buf[pos] = pk[j]; }
  __syncthreads();

  for (int i = tid; i < m; i += 512) {
    unsigned int v = buf[i];
    int b = (int)(v >> 24);
    bfile[gb[b] + (i - lb[b])] = v;
  }
}

// ---- stage 2: per-bucket counting sort (512 thr) -> csr16, base, cnt, dinv,
//      plus fused conversion x -> xh = bf16(dinv*x) ----
__global__ __launch_bounds__(512) void bucket_k(
    const unsigned int* __restrict__ bfile, const int* __restrict__ gcursor,
    unsigned short* __restrict__ csr16, int* __restrict__ basep,
    int* __restrict__ cntp, float* __restrict__ dinv,
    const float* __restrict__ x, uint4* __restrict__ xh, int n)
{
  __shared__ unsigned int ein[BCAP];
  __shared__ unsigned short eout[BCAP];
  __shared__ int h[256];
  __shared__ int p[256];
  __shared__ int cur[256];
  __shared__ float dvs[256];
  const int tid = threadIdx.x;
  const int b   = blockIdx.x;
  const int s   = b * BCAP;
  int L = gcursor[b] - s;
  if (L > BCAP) L = BCAP;

  for (int i = tid; i < L; i += 512) ein[i] = bfile[s + i];
  if (tid < 256) h[tid] = 0;
  __syncthreads();
  for (int i = tid; i < L; i += 512) atomicAdd(&h[(ein[i] >> 16) & 255], 1);
  __syncthreads();

  const int myc = (tid < 256) ? h[tid] : 0;
  if (tid < 256) p[tid] = myc;
  __syncthreads();
  for (int off = 1; off < 256; off <<= 1) {
    int t = (tid >= off && tid < 256) ? p[tid - off] : 0;
    __syncthreads();
    if (tid < 256) p[tid] += t;
    __syncthreads();
  }
  const int ex = (tid < 256) ? (p[tid] - myc) : 0;
  if (tid < 256) cur[tid] = ex;
  __syncthreads();

  for (int i = tid; i < L; i += 512) {
    unsigned int pk = ein[i];
    int pos = atomicAdd(&cur[(pk >> 16) & 255], 1);
    eout[pos] = (unsigned short)(pk & 0xffffu);
  }
  __syncthreads();

  for (int i = tid; i < L; i += 512) csr16[s + i] = eout[i];

  if (tid < 256) {
    const int node = b * 256 + tid;
    const float dvv = rsqrtf(1.0f + (float)myc);
    dvs[tid] = dvv;
    if (node < n) {
      basep[node] = s + ex;
      cntp[node]  = myc;
      dinv[node]  = dvv;
    }
  }
  __syncthreads();

  // fused conversion for this bucket's 256 nodes (coalesced)
  const float4* x4 = (const float4*)x;
#pragma unroll
  for (int i = 0; i < 4; ++i) {
    int slot = i * 512 + tid;          // 0..2047 = 256 nodes x 8 uint4 slots
    int ln = slot >> 3;
    int gn = b * 256 + ln;
    if (gn >= n) continue;
    int q = slot & 7;
    float4 v0 = x4[(size_t)gn * 16 + q * 2 + 0];
    float4 v1 = x4[(size_t)gn * 16 + q * 2 + 1];
    float dvx = dvs[ln];
    uint4 u;
    u.x = (unsigned int)f2bf(dvx * v0.x) | ((unsigned int)f2bf(dvx * v0.y) << 16);
    u.y = (unsigned int)f2bf(dvx * v0.z) | ((unsigned int)f2bf(dvx * v0.w) << 16);
    u.z = (unsigned int)f2bf(dvx * v1.x) | ((unsigned int)f2bf(dvx * v1.y) << 16);
    u.w = (unsigned int)f2bf(dvx * v1.z) | ((unsigned int)f2bf(dvx * v1.w) << 16);
    xh[(size_t)gn * 8 + q] = u;
  }
}

#define ACC8(acc, v) \
  acc[0] += bflo(v.x); acc[1] += bfhi(v.x); acc[2] += bflo(v.y); acc[3] += bfhi(v.y); \
  acc[4] += bflo(v.z); acc[5] += bfhi(v.z); acc[6] += bflo(v.w); acc[7] += bfhi(v.w);

// ---- fused layer: bf16 gather (8 lanes/node, 16B/lane = one 128B line/row),
//      fp32 accum, S tile -> LDS, in-block GEMM + bias + relu.
//      32 nodes / 256-thr block. OUTBF=1: bf16 prescaled out; else fp32. ----
template<int OUTBF>
__global__ __launch_bounds__(256) void fused_layer_k(
    const uint4* __restrict__ inh, const float* __restrict__ W,
    const float* __restrict__ bias, const unsigned short* __restrict__ csr16,
    const int* __restrict__ basep, const int* __restrict__ cntp,
    const float* __restrict__ dinv, void* __restrict__ outp, int n)
{
  __shared__ float Ws[DF * XS_LD];
  __shared__ float Ss[32 * XS_LD];
  const int tid = threadIdx.x;

#pragma unroll
  for (int i = 0; i < 4; ++i) {
    const int f4 = tid + 256 * i;
    const int k  = f4 >> 4;
    const int c0 = (f4 & 15) * 4;
    *(float4*)(Ws + k * XS_LD + c0) = *(const float4*)(W + (size_t)f4 * 4);
  }

  const int nl   = tid >> 3;            // 0..31
  const int q    = tid & 7;             // 0..7
  const int node = blockIdx.x * 32 + nl;
  const bool valid = (node < n);
  float dv = 0.f;

  if (valid) {
    float a[8] = {0,0,0,0,0,0,0,0};
    float b2[8] = {0,0,0,0,0,0,0,0};
    dv = dinv[node];
    {
      uint4 v = inh[(size_t)node * 8 + q];          // self term (prescaled)
      ACC8(a, v)
    }
    const int s = basep[node], c = cntp[node];
    int k = 0;
    for (; k + 4 <= c; k += 4) {
      int r0 = (int)csr16[s + k + 0], r1 = (int)csr16[s + k + 1];
      int r2 = (int)csr16[s + k + 2], r3 = (int)csr16[s + k + 3];
      uint4 v0 = inh[(size_t)r0 * 8 + q];
      uint4 v1 = inh[(size_t)r1 * 8 + q];
      uint4 v2 = inh[(size_t)r2 * 8 + q];
      uint4 v3 = inh[(size_t)r3 * 8 + q];
      ACC8(a, v0) ACC8(b2, v1) ACC8(a, v2) ACC8(b2, v3)
    }
    for (; k < c; ++k) {
      int r = (int)csr16[s + k];
      uint4 v = inh[(size_t)r * 8 + q];
      ACC8(a, v)
    }
    float4 s0 = make_float4(dv * (a[0] + b2[0]), dv * (a[1] + b2[1]),
                            dv * (a[2] + b2[2]), dv * (a[3] + b2[3]));
    float4 s1 = make_float4(dv * (a[4] + b2[4]), dv * (a[5] + b2[5]),
                            dv * (a[6] + b2[6]), dv * (a[7] + b2[7]));
    *(float4*)(Ss + nl * XS_LD + q * 8 + 0) = s0;
    *(float4*)(Ss + nl * XS_LD + q * 8 + 4) = s1;
  }
  __syncthreads();

  float4 o0 = ((const float4*)bias)[q * 2 + 0];
  float4 o1 = ((const float4*)bias)[q * 2 + 1];
#pragma unroll 16
  for (int k = 0; k < DF; ++k) {
    const float sk = Ss[nl * XS_LD + k];
    const float4 w0 = *(const float4*)(Ws + k * XS_LD + q * 8 + 0);
    const float4 w1 = *(const float4*)(Ws + k * XS_LD + q * 8 + 4);
    o0.x += sk * w0.x; o0.y += sk * w0.y; o0.z += sk * w0.z; o0.w += sk * w0.w;
    o1.x += sk * w1.x; o1.y += sk * w1.y; o1.z += sk * w1.z; o1.w += sk * w1.w;
  }
  if (valid) {
    o0.x = fmaxf(o0.x, 0.f); o0.y = fmaxf(o0.y, 0.f);
    o0.z = fmaxf(o0.z, 0.f); o0.w = fmaxf(o0.w, 0.f);
    o1.x = fmaxf(o1.x, 0.f); o1.y = fmaxf(o1.y, 0.f);
    o1.z = fmaxf(o1.z, 0.f); o1.w = fmaxf(o1.w, 0.f);
    if (OUTBF) {
      uint4 u;
      u.x = (unsigned int)f2bf(dv * o0.x) | ((unsigned int)f2bf(dv * o0.y) << 16);
      u.y = (unsigned int)f2bf(dv * o0.z) | ((unsigned int)f2bf(dv * o0.w) << 16);
      u.z = (unsigned int)f2bf(dv * o1.x) | ((unsigned int)f2bf(dv * o1.y) << 16);
      u.w = (unsigned int)f2bf(dv * o1.z) | ((unsigned int)f2bf(dv * o1.w) << 16);
      ((uint4*)outp)[(size_t)node * 8 + q] = u;
    } else {
      ((float4*)outp)[(size_t)node * 16 + q * 2 + 0] = o0;
      ((float4*)outp)[(size_t)node * 16 + q * 2 + 1] = o1;
    }
  }
}

extern "C" void kernel_launch(void* const* d_in, const int* in_sizes, int n_in,
                              void* d_out, int out_size, void* d_ws, size_t ws_size,
                              hipStream_t stream) {
  const float* x  = (const float*)d_in[0];
  const float* W1 = (const float*)d_in[1];
  const float* b1 = (const float*)d_in[2];
  const float* W2 = (const float*)d_in[3];
  const float* b2 = (const float*)d_in[4];
  const int*   ei = (const int*)d_in[5];

  const int n = in_sizes[0] / DF;        // 50000
  const int E = in_sizes[5] / 2;         // 800000
  const int* rows = ei;
  const int* cols = ei + E;
  const int nb = (n + 255) >> 8;         // 196 buckets
  const int eblocks = (E + ECHUNK - 1) / ECHUNK;

  char* w = (char*)d_ws;
  size_t off = 0;
  auto alloc = [&](size_t bytes) { char* p = w + off; off = (off + bytes + 255) & ~(size_t)255; return p; };
  float* dinv    = (float*)alloc((size_t)n * 4);
  int*   cntp    = (int*)  alloc((size_t)n * 4);
  int*   basep   = (int*)  alloc((size_t)n * 4);
  int*   gcursor = (int*)  alloc(256 * 4);
  unsigned int*   bfile = (unsigned int*)  alloc((size_t)nb * BCAP * 4);
  unsigned short* csr16 = (unsigned short*)alloc((size_t)nb * BCAP * 2 + 64);
  uint4* xh      = (uint4*)alloc((size_t)n * DF * 2);   // 6.4 MB bf16
  uint4* zh      = (uint4*)alloc((size_t)n * DF * 2);   // 6.4 MB bf16

  // ---- CSR build + dinv + x conversion ----
  init_cur_k<<<1, 256, 0, stream>>>(gcursor);
  part_k<<<eblocks, 512, 0, stream>>>(rows, cols, gcursor, bfile, E);
  bucket_k<<<nb, 512, 0, stream>>>(bfile, gcursor, csr16, basep, cntp, dinv, x, xh, n);

  const int lay_blocks = (n + 31) / 32;   // 1563

  // ---- layer 1: xh -> zh (bf16, prescaled) ----
  fused_layer_k<1><<<lay_blocks, 256, 0, stream>>>(xh, W1, b1, csr16, basep, cntp, dinv, zh, n);
  // ---- layer 2: zh -> d_out (fp32) ----
  fused_layer_k<0><<<lay_blocks, 256, 0, stream>>>(zh, W2, b2, csr16, basep, cntp, dinv, d_out, n);
}